// Round 14
// baseline (505.493 us; speedup 1.0000x reference)
//
#include <hip/hip_runtime.h>

// L2 self-attention. Inputs/outputs FP32; compute bf16 MFMA, fp32 accumulate.
// B=2 N=2048 D=1024 H=16 hd=64.
// R12: batch-fused QKV GEMM, 64x128-tile out-projection, fused weight cvt.
// R14: log2e folded into Q/K: p = exp2(-sqrt(d2')) one trans op.
// R15/R17: XOR swizzle + XCD-aware decode (FETCH 70.8->12.6MB).
// Ladder: attn3=84.0, attn4(32q)=84.0, attn5(+swz+xcd)=77.8 BEST,
// attn6(key-split)=85.8, attn7(dbuf)=81.5, attn9(16q,4blk/CU)=90.7.
// attn9 falsified the TLP theory: occupancy 18->36% yet dur UP; per-query
// staging doubled (conflicts 4.19->8.39M) -> the staging+barrier tax
// scales with block count and eats every restructuring gain.
// R26: attn_g = NO-LDS attention. After the XCD remap each XCD's K+V is
// 2MB, fully L2-resident (FETCH 12.6MB proves it); guide m169: staging
// L2-fit data is pure overhead. attn_c's verified global-load loop (zero
// barriers, zero staging, independent waves) + attn9's verified XCD
// decode/bf16 epilogue. 1024 blocks, 16 waves/CU, no LDS occupancy cap.

typedef __attribute__((ext_vector_type(8))) short sh8;   // 8 bf16 (4 VGPRs)
typedef __attribute__((ext_vector_type(4))) short sh4;   // 4 bf16 (2 VGPRs)
typedef __attribute__((ext_vector_type(4))) float f4;    // 4 fp32

#define QK_SCALE 1.44269504f       // log2(e); folded into Q and K
#define D2_CLAMP 2.0814e-12f       // 1e-12 * log2(e)^2 (Tier C path only)

__device__ __forceinline__ float bf2f(short s) {
  union { unsigned u; float f; } c;
  c.u = ((unsigned)(unsigned short)s) << 16;
  return c.f;
}
// fast bf16 round: half-up (2 VALU ops); <=1 ulp vs RNE, budget 2.4e-3.
__device__ __forceinline__ short f2bf(float f) {
  union { float f; unsigned u; } c;
  c.f = f;
  return (short)((c.u + 0x8000u) >> 16);
}
__device__ __forceinline__ sh8 pack8(f4 a, f4 b) {
  sh8 r;
  r[0] = f2bf(a[0]); r[1] = f2bf(a[1]); r[2] = f2bf(a[2]); r[3] = f2bf(a[3]);
  r[4] = f2bf(b[0]); r[5] = f2bf(b[1]); r[6] = f2bf(b[2]); r[7] = f2bf(b[3]);
  return r;
}
// exp2(-x): one v_exp_f32, fneg folded into source modifier by the compiler.
__device__ __forceinline__ float exp2neg(float x) {
  return __builtin_amdgcn_exp2f(-x);
}

// async global->LDS, 16B per lane; LDS dest = wave-uniform base + lane*16
#define GLDS16(g, l)                                                      \
  __builtin_amdgcn_global_load_lds(                                       \
      (__attribute__((address_space(1))) void*)(void*)(g),                \
      (__attribute__((address_space(3))) void*)(void*)(l), 16, 0, 0)

// ---------------------------------------------------------------------------
// fp32 -> bf16 elementwise (n multiple of 8)
// ---------------------------------------------------------------------------
__global__ __launch_bounds__(256) void cvt_bf16(const float* __restrict__ src,
                                                short* __restrict__ dst, int n) {
  const int i = (blockIdx.x * 256 + threadIdx.x) * 8;
  if (i < n)
    *(sh8*)(dst + i) = pack8(*(const f4*)(src + i), *(const f4*)(src + i + 4));
}

// 4 weight matrices (1M elems each) -> contiguous bf16 dst, one launch.
__global__ __launch_bounds__(256) void cvt_w4(
    const float* __restrict__ wq, const float* __restrict__ wk,
    const float* __restrict__ wv, const float* __restrict__ wo,
    short* __restrict__ dst) {
  const float* srcs[4] = {wq, wk, wv, wo};
  const float* s = srcs[blockIdx.y];
  short* d = dst + (size_t)blockIdx.y * 1048576;
  const int i = (blockIdx.x * 256 + threadIdx.x) * 8;
  *(sh8*)(d + i) = pack8(*(const f4*)(s + i), *(const f4*)(s + i + 4));
}

// ---------------------------------------------------------------------------
// QKV projection, fp32 inputs, batch-fused (M=4096 when grid.y=32).
// Epilogue: batch = m>>11, head slot = batch*16 + hl. (Tier C: m<2048 -> 0.)
// Q,K outputs scaled by log2(e) so attn can use exp2 directly.
// ---------------------------------------------------------------------------
__global__ __launch_bounds__(256) void gemm_qkvp(
    const float* __restrict__ X, const float* __restrict__ Wq,
    const float* __restrict__ Bq, const float* __restrict__ Wk,
    const float* __restrict__ Bk, const float* __restrict__ Wv,
    const float* __restrict__ Bv, short* __restrict__ Qp,
    short* __restrict__ Kp, short* __restrict__ Vtp, int w0, int nblkP) {
  __shared__ short As[128 * 32];
  __shared__ short Bs[128 * 32];
  const int t = threadIdx.x;
  const int wave = t >> 6;
  const int lane = t & 63;
  const int l15 = lane & 15;
  const int quad = lane >> 4;
  const int m0 = blockIdx.y * 128;
  const int which = blockIdx.x / nblkP;
  const int n0l = (blockIdx.x % nblkP) * 128;
  const int wrow0 = w0 + n0l;
  const float* W = (which == 0) ? Wq : ((which == 1) ? Wk : Wv);
  const float* Bias = (which == 0) ? Bq : ((which == 1) ? Bk : Bv);
  const float qkscl = (which == 2) ? 1.0f : QK_SCALE;
  const int wm = (wave & 1) * 64;
  const int wn = (wave >> 1) * 64;

  f4 acc[4][4];
#pragma unroll
  for (int i = 0; i < 4; ++i)
#pragma unroll
    for (int j = 0; j < 4; ++j) acc[i][j] = (f4){0.f, 0.f, 0.f, 0.f};

  const float* ag = X + (size_t)(m0 + (t >> 2)) * 1024 + (t & 3) * 8;
  const float* bg = W + (size_t)(wrow0 + (t >> 2)) * 1024 + (t & 3) * 8;

  for (int kt = 0; kt < 1024; kt += 32) {
    const sh8 a0 = pack8(*(const f4*)(ag + kt), *(const f4*)(ag + kt + 4));
    const sh8 a1 =
        pack8(*(const f4*)(ag + 65536 + kt), *(const f4*)(ag + 65536 + kt + 4));
    const sh8 b0 = pack8(*(const f4*)(bg + kt), *(const f4*)(bg + kt + 4));
    const sh8 b1 =
        pack8(*(const f4*)(bg + 65536 + kt), *(const f4*)(bg + 65536 + kt + 4));
    __syncthreads();
    *(sh8*)(As + t * 8) = a0;
    *(sh8*)(As + 2048 + t * 8) = a1;
    *(sh8*)(Bs + t * 8) = b0;
    *(sh8*)(Bs + 2048 + t * 8) = b1;
    __syncthreads();
    sh8 af[4], bf[4];
#pragma unroll
    for (int i = 0; i < 4; ++i) {
      af[i] = *(const sh8*)(As + (wm + i * 16 + l15) * 32 + quad * 8);
      bf[i] = *(const sh8*)(Bs + (wn + i * 16 + l15) * 32 + quad * 8);
    }
#pragma unroll
    for (int i = 0; i < 4; ++i)
#pragma unroll
      for (int j = 0; j < 4; ++j)
        acc[i][j] =
            __builtin_amdgcn_mfma_f32_16x16x32_bf16(af[i], bf[j], acc[i][j], 0, 0, 0);
  }

#pragma unroll
  for (int j = 0; j < 4; ++j) {
    const int ngl = n0l + wn + j * 16 + l15;
    const float bias = Bias[w0 + ngl];
    const int hl = ngl >> 6;
    const int d = ngl & 63;
#pragma unroll
    for (int i = 0; i < 4; ++i) {
#pragma unroll
      for (int r = 0; r < 4; ++r) {
        const int m = m0 + wm + i * 16 + quad * 4 + r;
        const int slot = (m >> 11) * 16 + hl;   // batch*16 + head
        const int mm = m & 2047;
        const short o = f2bf((acc[i][j][r] + bias) * qkscl);
        if (which == 0)
          Qp[((size_t)slot * 2048 + mm) * 64 + d] = o;
        else if (which == 1)
          Kp[((size_t)slot * 2048 + mm) * 64 + d] = o;
        else
          Vtp[((size_t)slot * 64 + d) * 2048 + mm] = o;
      }
    }
  }
}

// ---------------------------------------------------------------------------
// QKV projection, bf16 inputs (Tier A2), batch-fused: GLDS16 both operands.
// Q,K outputs scaled by log2(e).
// ---------------------------------------------------------------------------
__global__ __launch_bounds__(256) void gemm_qkv_bf(
    const short* __restrict__ X, const short* __restrict__ Wq,
    const float* __restrict__ Bq, const short* __restrict__ Wk,
    const float* __restrict__ Bk, const short* __restrict__ Wv,
    const float* __restrict__ Bv, short* __restrict__ Qp,
    short* __restrict__ Kp, short* __restrict__ Vtp) {
  __shared__ short As[128 * 32];
  __shared__ short Bs[128 * 32];
  const int t = threadIdx.x;
  const int wave = t >> 6;
  const int lane = t & 63;
  const int l15 = lane & 15;
  const int quad = lane >> 4;
  const int m0 = blockIdx.y * 128;       // [0,4096)
  const int which = blockIdx.x >> 3;     // 0=Q 1=K 2=V
  const int n0l = (blockIdx.x & 7) * 128;
  const short* W = (which == 0) ? Wq : ((which == 1) ? Wk : Wv);
  const float* Bias = (which == 0) ? Bq : ((which == 1) ? Bk : Bv);
  const float qkscl = (which == 2) ? 1.0f : QK_SCALE;
  const int wm = (wave & 1) * 64;
  const int wn = (wave >> 1) * 64;

  f4 acc[4][4];
#pragma unroll
  for (int i = 0; i < 4; ++i)
#pragma unroll
    for (int j = 0; j < 4; ++j) acc[i][j] = (f4){0.f, 0.f, 0.f, 0.f};

  const short* ag = X + (size_t)(m0 + (t >> 2)) * 1024 + (t & 3) * 8;
  const short* bg = W + (size_t)(n0l + (t >> 2)) * 1024 + (t & 3) * 8;
  short* al = As + wave * 512;
  short* bl = Bs + wave * 512;

  for (int kt = 0; kt < 1024; kt += 32) {
    __syncthreads();
    GLDS16(ag + kt, al);
    GLDS16(ag + 65536 + kt, al + 2048);
    GLDS16(bg + kt, bl);
    GLDS16(bg + 65536 + kt, bl + 2048);
    __syncthreads();
    sh8 af[4], bf[4];
#pragma unroll
    for (int i = 0; i < 4; ++i) {
      af[i] = *(const sh8*)(As + (wm + i * 16 + l15) * 32 + quad * 8);
      bf[i] = *(const sh8*)(Bs + (wn + i * 16 + l15) * 32 + quad * 8);
    }
#pragma unroll
    for (int i = 0; i < 4; ++i)
#pragma unroll
      for (int j = 0; j < 4; ++j)
        acc[i][j] =
            __builtin_amdgcn_mfma_f32_16x16x32_bf16(af[i], bf[j], acc[i][j], 0, 0, 0);
  }

#pragma unroll
  for (int j = 0; j < 4; ++j) {
    const int ngl = n0l + wn + j * 16 + l15;
    const float bias = Bias[ngl];
    const int hl = ngl >> 6;
    const int d = ngl & 63;
#pragma unroll
    for (int i = 0; i < 4; ++i) {
#pragma unroll
      for (int r = 0; r < 4; ++r) {
        const int m = m0 + wm + i * 16 + quad * 4 + r;
        const int slot = (m >> 11) * 16 + hl;
        const int mm = m & 2047;
        const short o = f2bf((acc[i][j][r] + bias) * qkscl);
        if (which == 0)
          Qp[((size_t)slot * 2048 + mm) * 64 + d] = o;
        else if (which == 1)
          Kp[((size_t)slot * 2048 + mm) * 64 + d] = o;
        else
          Vtp[((size_t)slot * 64 + d) * 2048 + mm] = o;
      }
    }
  }
}

// ---------------------------------------------------------------------------
// Sums of squares of bf16-rounded (scaled) Q and K rows. R rows per tensor.
// ---------------------------------------------------------------------------
__global__ __launch_bounds__(256) void sumsq(const short* __restrict__ Qp,
                                             const short* __restrict__ Kp,
                                             float* __restrict__ q2a,
                                             float* __restrict__ k2a, int R) {
  const int tid = blockIdx.x * 256 + threadIdx.x;
  const bool isQ = tid < R;
  const int r = isQ ? tid : tid - R;
  const short* p = (isQ ? Qp : Kp) + (size_t)r * 64;
  float s = 0.f;
#pragma unroll
  for (int i = 0; i < 8; ++i) {
    sh8 v = *(const sh8*)(p + i * 8);
#pragma unroll
    for (int j = 0; j < 8; ++j) {
      float f = bf2f(v[j]);
      s = fmaf(f, f, s);
    }
  }
  (isQ ? q2a : k2a)[r] = s;
}

// ---------------------------------------------------------------------------
// attn_g: NO-LDS global-load attention (Tier A). 16 q/wave, 4-wave blocks,
// 1024 blocks = 4 blocks/CU = 16 waves/CU; zero barriers, zero staging.
// K+V (2MB/XCD) is L2-resident after XCD decode: xcd=id&7 owns 4 head-slots
// (verified R17), qt=(id>>3)&31, hb=xcd*4+(id>>8) (disjoint bits, bijective).
// Loop body = attn_c's verified global-load loop (fabs clamp variant).
// S^T = MFMA(A=Kfrag, B=Qfrag); O C-layout row=query, col=vdim chunk.
// p = exp2(-sqrt(|d2'|)), log2e pre-folded into Q/K. launch_bounds(256,4):
// VGPR cap 128 either semantics; kernel needs ~70 -> no spill.
// ---------------------------------------------------------------------------
__global__ __launch_bounds__(256, 4) void attn_g(
    const short* __restrict__ Qp, const short* __restrict__ Kp,
    const short* __restrict__ Vtp, const float* __restrict__ q2a,
    const float* __restrict__ k2a, short* __restrict__ attH) {
  const int t = threadIdx.x;
  const int wave = t >> 6;
  const int lane = t & 63;
  const int l15 = lane & 15;
  const int quad = lane >> 4;
  const int id = blockIdx.x;             // [0,1024)
  const int qt = (id >> 3) & 31;         // query tile (64 q each)
  const int hb_ = (id & 7) * 4 + (id >> 8);  // slot [0,32): xcd owns 4 slots
  const int hy = hb_ & 15;
  const int bz = hb_ >> 4;
  const size_t base = (size_t)hb_ * 2048;
  const int qrow = qt * 64 + wave * 16 + l15;

  const short* qp = Qp + (base + qrow) * 64 + quad * 8;
  const sh8 qf0 = *(const sh8*)qp;
  const sh8 qf1 = *(const sh8*)(qp + 32);
  const float q2 = q2a[base + qrow];

  float l_run = 0.f;
  f4 o0 = (f4){0.f, 0.f, 0.f, 0.f}, o1 = o0, o2 = o0, o3 = o0;

  const short* kbase = Kp + (base + l15) * 64 + quad * 8;
  const float* k2p = k2a + base + quad * 4;
  const short* vbase = Vtp + ((size_t)hb_ * 64 + l15) * 2048 + quad * 4;

  for (int j = 0; j < 2048; j += 16) {
    const sh8 kf0 = *(const sh8*)(kbase + (size_t)j * 64);
    const sh8 kf1 = *(const sh8*)(kbase + (size_t)j * 64 + 32);
    f4 st = (f4){0.f, 0.f, 0.f, 0.f};
    st = __builtin_amdgcn_mfma_f32_16x16x32_bf16(kf0, qf0, st, 0, 0, 0);
    st = __builtin_amdgcn_mfma_f32_16x16x32_bf16(kf1, qf1, st, 0, 0, 0);
    const f4 k2v = *(const f4*)(k2p + j);
    float p[4];
#pragma unroll
    for (int r = 0; r < 4; ++r) {
      const float d2 = fmaf(-2.f, st[r], q2 + k2v[r]);
      p[r] = exp2neg(__builtin_amdgcn_sqrtf(fabsf(d2)));
    }
    l_run += (p[0] + p[1]) + (p[2] + p[3]);
    sh4 pf;
#pragma unroll
    for (int r = 0; r < 4; ++r) pf[r] = f2bf(p[r]);
    const sh4 vf0 = *(const sh4*)(vbase + j);
    const sh4 vf1 = *(const sh4*)(vbase + 16 * 2048 + j);
    const sh4 vf2 = *(const sh4*)(vbase + 32 * 2048 + j);
    const sh4 vf3 = *(const sh4*)(vbase + 48 * 2048 + j);
    o0 = __builtin_amdgcn_mfma_f32_16x16x16bf16_1k(pf, vf0, o0, 0, 0, 0);
    o1 = __builtin_amdgcn_mfma_f32_16x16x16bf16_1k(pf, vf1, o1, 0, 0, 0);
    o2 = __builtin_amdgcn_mfma_f32_16x16x16bf16_1k(pf, vf2, o2, 0, 0, 0);
    o3 = __builtin_amdgcn_mfma_f32_16x16x16bf16_1k(pf, vf3, o3, 0, 0, 0);
  }

  l_run += __shfl_xor(l_run, 16);
  l_run += __shfl_xor(l_run, 32);
  const float il0 = 1.f / __shfl(l_run, quad * 4 + 0);
  const float il1 = 1.f / __shfl(l_run, quad * 4 + 1);
  const float il2 = 1.f / __shfl(l_run, quad * 4 + 2);
  const float il3 = 1.f / __shfl(l_run, quad * 4 + 3);

  const int rowbase = qt * 64 + wave * 16 + quad * 4;
  const f4* oc[4] = {&o0, &o1, &o2, &o3};
  const float il[4] = {il0, il1, il2, il3};
  const size_t off0 = ((size_t)bz * 2048 + rowbase) * 1024 + hy * 64 + l15;
#pragma unroll
  for (int c = 0; c < 4; ++c)
#pragma unroll
    for (int r = 0; r < 4; ++r)
      attH[off0 + (size_t)r * 1024 + c * 16] = f2bf((*oc[c])[r] * il[r]);
}

// ---------------------------------------------------------------------------
// attn (global-load variant) for Tier C only: fp32 att into d_out slice.
// Inputs pre-scaled by log2(e): exp2 path.
// ---------------------------------------------------------------------------
__global__ __launch_bounds__(256) void attn_c(
    const short* __restrict__ Qp, const short* __restrict__ Kp,
    const short* __restrict__ Vtp, const float* __restrict__ q2a,
    const float* __restrict__ k2a, float* __restrict__ attF, int col0) {
  const int t = threadIdx.x;
  const int wave = t >> 6;
  const int lane = t & 63;
  const int l15 = lane & 15;
  const int quad = lane >> 4;
  const int hy = blockIdx.y;
  const int qt = blockIdx.x;
  const size_t base = (size_t)hy * 2048;
  const int qrow = qt * 64 + wave * 16 + l15;

  const short* qp = Qp + (base + qrow) * 64 + quad * 8;
  const sh8 qf0 = *(const sh8*)qp;
  const sh8 qf1 = *(const sh8*)(qp + 32);
  const float q2 = q2a[base + qrow];

  float l_run = 0.f;
  f4 o0 = (f4){0.f, 0.f, 0.f, 0.f}, o1 = o0, o2 = o0, o3 = o0;

  const short* kbase = Kp + (base + l15) * 64 + quad * 8;
  const float* k2p = k2a + base + quad * 4;
  const short* vbase = Vtp + ((size_t)hy * 64 + l15) * 2048 + quad * 4;

  for (int j = 0; j < 2048; j += 16) {
    const sh8 kf0 = *(const sh8*)(kbase + (size_t)j * 64);
    const sh8 kf1 = *(const sh8*)(kbase + (size_t)j * 64 + 32);
    f4 st = (f4){0.f, 0.f, 0.f, 0.f};
    st = __builtin_amdgcn_mfma_f32_16x16x32_bf16(kf0, qf0, st, 0, 0, 0);
    st = __builtin_amdgcn_mfma_f32_16x16x32_bf16(kf1, qf1, st, 0, 0, 0);
    const f4 k2v = *(const f4*)(k2p + j);
    float p[4];
#pragma unroll
    for (int r = 0; r < 4; ++r) {
      const float d2 = fmaxf(fmaf(-2.f, st[r], q2 + k2v[r]), D2_CLAMP);
      p[r] = exp2neg(__builtin_amdgcn_sqrtf(d2));
    }
    l_run += (p[0] + p[1]) + (p[2] + p[3]);
    sh4 pf;
#pragma unroll
    for (int r = 0; r < 4; ++r) pf[r] = f2bf(p[r]);
    const sh4 vf0 = *(const sh4*)(vbase + j);
    const sh4 vf1 = *(const sh4*)(vbase + 16 * 2048 + j);
    const sh4 vf2 = *(const sh4*)(vbase + 32 * 2048 + j);
    const sh4 vf3 = *(const sh4*)(vbase + 48 * 2048 + j);
    o0 = __builtin_amdgcn_mfma_f32_16x16x16bf16_1k(pf, vf0, o0, 0, 0, 0);
    o1 = __builtin_amdgcn_mfma_f32_16x16x16bf16_1k(pf, vf1, o1, 0, 0, 0);
    o2 = __builtin_amdgcn_mfma_f32_16x16x16bf16_1k(pf, vf2, o2, 0, 0, 0);
    o3 = __builtin_amdgcn_mfma_f32_16x16x16bf16_1k(pf, vf3, o3, 0, 0, 0);
  }

  l_run += __shfl_xor(l_run, 16);
  l_run += __shfl_xor(l_run, 32);
  const float il0 = 1.f / __shfl(l_run, quad * 4 + 0);
  const float il1 = 1.f / __shfl(l_run, quad * 4 + 1);
  const float il2 = 1.f / __shfl(l_run, quad * 4 + 2);
  const float il3 = 1.f / __shfl(l_run, quad * 4 + 3);

  const int rowbase = qt * 64 + wave * 16 + quad * 4;
  const f4* oc[4] = {&o0, &o1, &o2, &o3};
  const float il[4] = {il0, il1, il2, il3};
  const size_t off0 = (size_t)rowbase * 1024 + col0 + hy * 64 + l15;
#pragma unroll
  for (int c = 0; c < 4; ++c)
#pragma unroll
    for (int r = 0; r < 4; ++r)
      attF[off0 + (size_t)r * 1024 + c * 16] = (*oc[c])[r] * il[r];
}

// ---------------------------------------------------------------------------
// Output projection, 64x128 tile (512 blocks = 2/CU). Tier A2: bf16 Wo.
// Wave tile 32x64: acc[2][4].
// ---------------------------------------------------------------------------
__global__ __launch_bounds__(256) void gemm_out_bf64(
    const short* __restrict__ A, const short* __restrict__ W,
    const float* __restrict__ Bias, float* __restrict__ Out) {
  __shared__ short As[64 * 32];
  __shared__ short Bs[128 * 32];
  const int t = threadIdx.x;
  const int wave = t >> 6;
  const int lane = t & 63;
  const int l15 = lane & 15;
  const int quad = lane >> 4;
  const int m0 = blockIdx.y * 64;
  const int n0 = blockIdx.x * 128;
  const int wm = (wave & 1) * 32;
  const int wn = (wave >> 1) * 64;

  f4 acc[2][4];
#pragma unroll
  for (int i = 0; i < 2; ++i)
#pragma unroll
    for (int j = 0; j < 4; ++j) acc[i][j] = (f4){0.f, 0.f, 0.f, 0.f};

  const short* ag = A + (size_t)(m0 + (t >> 2)) * 1024 + (t & 3) * 8;
  const short* bg = W + (size_t)(n0 + (t >> 2)) * 1024 + (t & 3) * 8;
  short* al = As + wave * 512;
  short* bl = Bs + wave * 512;

  for (int kt = 0; kt < 1024; kt += 32) {
    __syncthreads();
    GLDS16(ag + kt, al);          // A: 64x32 = one issue
    GLDS16(bg + kt, bl);          // B: 128x32 = two issues
    GLDS16(bg + 65536 + kt, bl + 2048);
    __syncthreads();
    sh8 af[2], bf[4];
#pragma unroll
    for (int i = 0; i < 2; ++i)
      af[i] = *(const sh8*)(As + (wm + i * 16 + l15) * 32 + quad * 8);
#pragma unroll
    for (int j = 0; j < 4; ++j)
      bf[j] = *(const sh8*)(Bs + (wn + j * 16 + l15) * 32 + quad * 8);
#pragma unroll
    for (int i = 0; i < 2; ++i)
#pragma unroll
      for (int j = 0; j < 4; ++j)
        acc[i][j] =
            __builtin_amdgcn_mfma_f32_16x16x32_bf16(af[i], bf[j], acc[i][j], 0, 0, 0);
  }

#pragma unroll
  for (int j = 0; j < 4; ++j) {
    const int n = n0 + wn + j * 16 + l15;
    const float bias = Bias[n];
#pragma unroll
    for (int i = 0; i < 2; ++i) {
#pragma unroll
      for (int r = 0; r < 4; ++r) {
        const int m = m0 + wm + i * 16 + quad * 4 + r;
        Out[(size_t)m * 1024 + n] = acc[i][j][r] + bias;
      }
    }
  }
}

// Tier A variant: fp32 Wo with pack8 staging, same 64x128 tile.
__global__ __launch_bounds__(256) void gemm_out_ws64(
    const short* __restrict__ A, const float* __restrict__ W,
    const float* __restrict__ Bias, float* __restrict__ Out) {
  __shared__ short As[64 * 32];
  __shared__ short Bs[128 * 32];
  const int t = threadIdx.x;
  const int wave = t >> 6;
  const int lane = t & 63;
  const int l15 = lane & 15;
  const int quad = lane >> 4;
  const int m0 = blockIdx.y * 64;
  const int n0 = blockIdx.x * 128;
  const int wm = (wave & 1) * 32;
  const int wn = (wave >> 1) * 64;

  f4 acc[2][4];
#pragma unroll
  for (int i = 0; i < 2; ++i)
#pragma unroll
    for (int j = 0; j < 4; ++j) acc[i][j] = (f4){0.f, 0.f, 0.f, 0.f};

  const short* ag = A + (size_t)(m0 + (t >> 2)) * 1024 + (t & 3) * 8;
  const float* bg = W + (size_t)(n0 + (t >> 2)) * 1024 + (t & 3) * 8;
  short* al = As + wave * 512;

  for (int kt = 0; kt < 1024; kt += 32) {
    const sh8 b0 = pack8(*(const f4*)(bg + kt), *(const f4*)(bg + kt + 4));
    const sh8 b1 =
        pack8(*(const f4*)(bg + 65536 + kt), *(const f4*)(bg + 65536 + kt + 4));
    __syncthreads();
    GLDS16(ag + kt, al);
    *(sh8*)(Bs + t * 8) = b0;
    *(sh8*)(Bs + 2048 + t * 8) = b1;
    __syncthreads();
    sh8 af[2], bf[4];
#pragma unroll
    for (int i = 0; i < 2; ++i)
      af[i] = *(const sh8*)(As + (wm + i * 16 + l15) * 32 + quad * 8);
#pragma unroll
    for (int j = 0; j < 4; ++j)
      bf[j] = *(const sh8*)(Bs + (wn + j * 16 + l15) * 32 + quad * 8);
#pragma unroll
    for (int i = 0; i < 2; ++i)
#pragma unroll
      for (int j = 0; j < 4; ++j)
        acc[i][j] =
            __builtin_amdgcn_mfma_f32_16x16x32_bf16(af[i], bf[j], acc[i][j], 0, 0, 0);
  }

#pragma unroll
  for (int j = 0; j < 4; ++j) {
    const int n = n0 + wn + j * 16 + l15;
    const float bias = Bias[n];
#pragma unroll
    for (int i = 0; i < 2; ++i) {
#pragma unroll
      for (int r = 0; r < 4; ++r) {
        const int m = m0 + wm + i * 16 + quad * 4 + r;
        Out[(size_t)m * 1024 + n] = acc[i][j][r] + bias;
      }
    }
  }
}

// ---------------------------------------------------------------------------
// Fallback in-place output projection (Tier C).
// ---------------------------------------------------------------------------
__global__ __launch_bounds__(256) void outproj_inplace(
    float* __restrict__ AO, const float* __restrict__ W,
    const float* __restrict__ Bias) {
  __shared__ short attS[16 * 264];
  const int t = threadIdx.x;
  const int wave = t >> 6;
  const int lane = t & 63;
  const int l15 = lane & 15;
  const int quad = lane >> 4;
  const int m0 = blockIdx.x * 16;
  const int n0w = wave * 256;

  f4 acc[16];
#pragma unroll
  for (int i = 0; i < 16; ++i) acc[i] = (f4){0.f, 0.f, 0.f, 0.f};

  for (int kc = 0; kc < 4; ++kc) {
    __syncthreads();
#pragma unroll
    for (int i = 0; i < 2; ++i) {
      const int e = i * 2048 + t * 8;
      const int row = e >> 8;
      const int col = e & 255;
      const float* src = AO + (size_t)(m0 + row) * 1024 + kc * 256 + col;
      *(sh8*)(attS + row * 264 + col) =
          pack8(*(const f4*)src, *(const f4*)(src + 4));
    }
    __syncthreads();
    for (int ktl = 0; ktl < 256; ktl += 32) {
      const sh8 af = *(const sh8*)(attS + l15 * 264 + ktl + quad * 8);
      const int kt = kc * 256 + ktl;
#pragma unroll
      for (int nf = 0; nf < 16; ++nf) {
        const float* wp = W + (size_t)(n0w + nf * 16 + l15) * 1024 + kt + quad * 8;
        const sh8 bf = pack8(*(const f4*)wp, *(const f4*)(wp + 4));
        acc[nf] = __builtin_amdgcn_mfma_f32_16x16x32_bf16(af, bf, acc[nf], 0, 0, 0);
      }
    }
  }
  __syncthreads();

#pragma unroll
  for (int nf = 0; nf < 16; ++nf) {
    const int n = n0w + nf * 16 + l15;
    const float bias = Bias[n];
#pragma unroll
    for (int r = 0; r < 4; ++r) {
      const int m = m0 + quad * 4 + r;
      AO[(size_t)m * 1024 + n] = acc[nf][r] + bias;
    }
  }
}

// ---------------------------------------------------------------------------
extern "C" void kernel_launch(void* const* d_in, const int* in_sizes, int n_in,
                              void* d_out, int out_size, void* d_ws,
                              size_t ws_size, hipStream_t stream) {
  const float* x = (const float*)d_in[0];
  const float* wq = (const float*)d_in[1];
  const float* bq = (const float*)d_in[2];
  const float* wk = (const float*)d_in[3];
  const float* bk = (const float*)d_in[4];
  const float* wv = (const float*)d_in[5];
  const float* bv = (const float*)d_in[6];
  const float* wo = (const float*)d_in[7];
  const float* bo = (const float*)d_in[8];
  float* out = (float*)d_out;

  const size_t NEED_A2 = 50855936ULL;  // A + Xbf 8MB + Wbf 8MB
  const size_t NEED_A = 34078720ULL;   // 24MB QKV(2b) + 8MB att + 512KB q2k2

  if (ws_size >= NEED_A) {
    short* Qp = (short*)d_ws;                 // [b*16+h][2048][64] bf16, 8MB
    short* Kp = Qp + 4194304;                 // 8MB
    short* Vtp = Kp + 4194304;                // [b*16+h][64][2048] bf16, 8MB
    short* attAll = Vtp + 4194304;            // [4096][1024] bf16, 8MB
    float* q2 = (float*)(attAll + 4194304);   // 256KB
    float* k2 = q2 + 65536;                   // 256KB

    if (ws_size >= NEED_A2) {
      short* Xb = (short*)(k2 + 65536);       // 4M bf16 = 8MB
      short* Wqb = Xb + 4194304;              // 4x 1M bf16, contiguous
      cvt_bf16<<<2048, 256, 0, stream>>>(x, Xb, 4194304);
      cvt_w4<<<dim3(512, 4), 256, 0, stream>>>(wq, wk, wv, wo, Wqb);
      gemm_qkv_bf<<<dim3(24, 32), 256, 0, stream>>>(
          Xb, Wqb, bq, Wqb + 1048576, bk, Wqb + 2097152, bv, Qp, Kp, Vtp);
      sumsq<<<512, 256, 0, stream>>>(Qp, Kp, q2, k2, 65536);
      attn_g<<<1024, 256, 0, stream>>>(Qp, Kp, Vtp, q2, k2, attAll);
      gemm_out_bf64<<<dim3(8, 64), 256, 0, stream>>>(attAll, Wqb + 3145728,
                                                     bo, out);
    } else {
      gemm_qkvp<<<dim3(24, 32), 256, 0, stream>>>(x, wq, bq, wk, bk, wv, bv,
                                                  Qp, Kp, Vtp, 0, 8);
      sumsq<<<512, 256, 0, stream>>>(Qp, Kp, q2, k2, 65536);
      attn_g<<<1024, 256, 0, stream>>>(Qp, Kp, Vtp, q2, k2, attAll);
      gemm_out_ws64<<<dim3(8, 64), 256, 0, stream>>>(attAll, wo, bo, out);
    }
  } else {
    // Tier C: small-ws fallback (att fp32 in d_out, in-place outproj).
    int G = 16;
    while (G > 2 && (size_t)G * 802816ULL > ws_size) G >>= 1;
    short* Qp = (short*)d_ws;
    short* Kp = Qp + (size_t)G * 131072;
    short* Vtp = Kp + (size_t)G * 131072;
    float* q2 = (float*)(Vtp + (size_t)G * 131072);
    float* k2 = q2 + (size_t)G * 2048;

    const int groups = 16 / G;
    for (int b = 0; b < 2; ++b) {
      const float* xb = x + (size_t)b * 2097152;
      float* attB = out + (size_t)b * 2097152;
      for (int g = 0; g < groups; ++g) {
        gemm_qkvp<<<dim3(3 * (G / 2), 16), 256, 0, stream>>>(
            xb, wq, bq, wk, bk, wv, bv, Qp, Kp, Vtp, g * G * 64, G / 2);
        sumsq<<<16 * G, 256, 0, stream>>>(Qp, Kp, q2, k2, G * 2048);
        attn_c<<<dim3(32, G), 256, 0, stream>>>(Qp, Kp, Vtp, q2, k2, attB,
                                                g * G * 64);
      }
    }
    outproj_inplace<<<256, 256, 0, stream>>>(out, wo, bo);
  }
}

// Round 15
// 226.002 us; speedup vs baseline: 2.2367x; 2.2367x over previous
//
#include <hip/hip_runtime.h>

// L2 self-attention. Inputs/outputs FP32; compute bf16 MFMA, fp32 accumulate.
// B=2 N=2048 D=1024 H=16 hd=64.
// R12: batch-fused QKV GEMM (768 blocks), 64x128-tile out-projection.
// R14: log2e folded into Q/K so p = exp2(-sqrt(d2')) is one trans op.
// R15: XOR-swizzled Ks/Vs (conflicts 6.29M->4.19M).
// R17: XCD-aware decode (FETCH 70.8->12.6MB). attn5 = 77.8us, total 228.6.
// Exploration ladder (all measured): attn3=84.0, attn4(32q)=84.0,
// attn5=77.8 BEST, attn6(key-split)=85.8, attn7(dbuf)=81.5,
// attn9(16q hi-occ)=90.7 (occupancy 2x but per-query staging 2x),
// attn_g(no-LDS)=363 (L2-latency serialization: MfmaUtil 5.7, all pipes
// idle -- LDS staging was the solution, not the tax).
// R27: REVERT to attn5 verbatim (R17's passing kernel) -- measured best;
// five structural perturbations failed to beat it.

typedef __attribute__((ext_vector_type(8))) short sh8;   // 8 bf16 (4 VGPRs)
typedef __attribute__((ext_vector_type(4))) short sh4;   // 4 bf16 (2 VGPRs)
typedef __attribute__((ext_vector_type(4))) float f4;    // 4 fp32

#define QK_SCALE 1.44269504f       // log2(e); folded into Q and K
#define D2_CLAMP 2.0814e-12f       // 1e-12 * log2(e)^2 (Tier C path only)

__device__ __forceinline__ float bf2f(short s) {
  union { unsigned u; float f; } c;
  c.u = ((unsigned)(unsigned short)s) << 16;
  return c.f;
}
// fast bf16 round: half-up (2 VALU ops); <=1 ulp vs RNE, budget 2.4e-3.
__device__ __forceinline__ short f2bf(float f) {
  union { float f; unsigned u; } c;
  c.f = f;
  return (short)((c.u + 0x8000u) >> 16);
}
__device__ __forceinline__ sh8 pack8(f4 a, f4 b) {
  sh8 r;
  r[0] = f2bf(a[0]); r[1] = f2bf(a[1]); r[2] = f2bf(a[2]); r[3] = f2bf(a[3]);
  r[4] = f2bf(b[0]); r[5] = f2bf(b[1]); r[6] = f2bf(b[2]); r[7] = f2bf(b[3]);
  return r;
}
// exp2(-x): one v_exp_f32, fneg folded into source modifier by the compiler.
__device__ __forceinline__ float exp2neg(float x) {
  return __builtin_amdgcn_exp2f(-x);
}

// async global->LDS, 16B per lane; LDS dest = wave-uniform base + lane*16
#define GLDS16(g, l)                                                      \
  __builtin_amdgcn_global_load_lds(                                       \
      (__attribute__((address_space(1))) void*)(void*)(g),                \
      (__attribute__((address_space(3))) void*)(void*)(l), 16, 0, 0)

// ---------------------------------------------------------------------------
// fp32 -> bf16 elementwise (n multiple of 8)
// ---------------------------------------------------------------------------
__global__ __launch_bounds__(256) void cvt_bf16(const float* __restrict__ src,
                                                short* __restrict__ dst, int n) {
  const int i = (blockIdx.x * 256 + threadIdx.x) * 8;
  if (i < n)
    *(sh8*)(dst + i) = pack8(*(const f4*)(src + i), *(const f4*)(src + i + 4));
}

// 4 weight matrices (1M elems each) -> contiguous bf16 dst, one launch.
__global__ __launch_bounds__(256) void cvt_w4(
    const float* __restrict__ wq, const float* __restrict__ wk,
    const float* __restrict__ wv, const float* __restrict__ wo,
    short* __restrict__ dst) {
  const float* srcs[4] = {wq, wk, wv, wo};
  const float* s = srcs[blockIdx.y];
  short* d = dst + (size_t)blockIdx.y * 1048576;
  const int i = (blockIdx.x * 256 + threadIdx.x) * 8;
  *(sh8*)(d + i) = pack8(*(const f4*)(s + i), *(const f4*)(s + i + 4));
}

// ---------------------------------------------------------------------------
// QKV projection, fp32 inputs, batch-fused (M=4096 when grid.y=32).
// Epilogue: batch = m>>11, head slot = batch*16 + hl. (Tier C: m<2048 -> 0.)
// Q,K outputs scaled by log2(e) so attn can use exp2 directly.
// ---------------------------------------------------------------------------
__global__ __launch_bounds__(256) void gemm_qkvp(
    const float* __restrict__ X, const float* __restrict__ Wq,
    const float* __restrict__ Bq, const float* __restrict__ Wk,
    const float* __restrict__ Bk, const float* __restrict__ Wv,
    const float* __restrict__ Bv, short* __restrict__ Qp,
    short* __restrict__ Kp, short* __restrict__ Vtp, int w0, int nblkP) {
  __shared__ short As[128 * 32];
  __shared__ short Bs[128 * 32];
  const int t = threadIdx.x;
  const int wave = t >> 6;
  const int lane = t & 63;
  const int l15 = lane & 15;
  const int quad = lane >> 4;
  const int m0 = blockIdx.y * 128;
  const int which = blockIdx.x / nblkP;
  const int n0l = (blockIdx.x % nblkP) * 128;
  const int wrow0 = w0 + n0l;
  const float* W = (which == 0) ? Wq : ((which == 1) ? Wk : Wv);
  const float* Bias = (which == 0) ? Bq : ((which == 1) ? Bk : Bv);
  const float qkscl = (which == 2) ? 1.0f : QK_SCALE;
  const int wm = (wave & 1) * 64;
  const int wn = (wave >> 1) * 64;

  f4 acc[4][4];
#pragma unroll
  for (int i = 0; i < 4; ++i)
#pragma unroll
    for (int j = 0; j < 4; ++j) acc[i][j] = (f4){0.f, 0.f, 0.f, 0.f};

  const float* ag = X + (size_t)(m0 + (t >> 2)) * 1024 + (t & 3) * 8;
  const float* bg = W + (size_t)(wrow0 + (t >> 2)) * 1024 + (t & 3) * 8;

  for (int kt = 0; kt < 1024; kt += 32) {
    const sh8 a0 = pack8(*(const f4*)(ag + kt), *(const f4*)(ag + kt + 4));
    const sh8 a1 =
        pack8(*(const f4*)(ag + 65536 + kt), *(const f4*)(ag + 65536 + kt + 4));
    const sh8 b0 = pack8(*(const f4*)(bg + kt), *(const f4*)(bg + kt + 4));
    const sh8 b1 =
        pack8(*(const f4*)(bg + 65536 + kt), *(const f4*)(bg + 65536 + kt + 4));
    __syncthreads();
    *(sh8*)(As + t * 8) = a0;
    *(sh8*)(As + 2048 + t * 8) = a1;
    *(sh8*)(Bs + t * 8) = b0;
    *(sh8*)(Bs + 2048 + t * 8) = b1;
    __syncthreads();
    sh8 af[4], bf[4];
#pragma unroll
    for (int i = 0; i < 4; ++i) {
      af[i] = *(const sh8*)(As + (wm + i * 16 + l15) * 32 + quad * 8);
      bf[i] = *(const sh8*)(Bs + (wn + i * 16 + l15) * 32 + quad * 8);
    }
#pragma unroll
    for (int i = 0; i < 4; ++i)
#pragma unroll
      for (int j = 0; j < 4; ++j)
        acc[i][j] =
            __builtin_amdgcn_mfma_f32_16x16x32_bf16(af[i], bf[j], acc[i][j], 0, 0, 0);
  }

#pragma unroll
  for (int j = 0; j < 4; ++j) {
    const int ngl = n0l + wn + j * 16 + l15;
    const float bias = Bias[w0 + ngl];
    const int hl = ngl >> 6;
    const int d = ngl & 63;
#pragma unroll
    for (int i = 0; i < 4; ++i) {
#pragma unroll
      for (int r = 0; r < 4; ++r) {
        const int m = m0 + wm + i * 16 + quad * 4 + r;
        const int slot = (m >> 11) * 16 + hl;   // batch*16 + head
        const int mm = m & 2047;
        const short o = f2bf((acc[i][j][r] + bias) * qkscl);
        if (which == 0)
          Qp[((size_t)slot * 2048 + mm) * 64 + d] = o;
        else if (which == 1)
          Kp[((size_t)slot * 2048 + mm) * 64 + d] = o;
        else
          Vtp[((size_t)slot * 64 + d) * 2048 + mm] = o;
      }
    }
  }
}

// ---------------------------------------------------------------------------
// QKV projection, bf16 inputs (Tier A2), batch-fused: GLDS16 both operands.
// Q,K outputs scaled by log2(e).
// ---------------------------------------------------------------------------
__global__ __launch_bounds__(256) void gemm_qkv_bf(
    const short* __restrict__ X, const short* __restrict__ Wq,
    const float* __restrict__ Bq, const short* __restrict__ Wk,
    const float* __restrict__ Bk, const short* __restrict__ Wv,
    const float* __restrict__ Bv, short* __restrict__ Qp,
    short* __restrict__ Kp, short* __restrict__ Vtp) {
  __shared__ short As[128 * 32];
  __shared__ short Bs[128 * 32];
  const int t = threadIdx.x;
  const int wave = t >> 6;
  const int lane = t & 63;
  const int l15 = lane & 15;
  const int quad = lane >> 4;
  const int m0 = blockIdx.y * 128;       // [0,4096)
  const int which = blockIdx.x >> 3;     // 0=Q 1=K 2=V
  const int n0l = (blockIdx.x & 7) * 128;
  const short* W = (which == 0) ? Wq : ((which == 1) ? Wk : Wv);
  const float* Bias = (which == 0) ? Bq : ((which == 1) ? Bk : Bv);
  const float qkscl = (which == 2) ? 1.0f : QK_SCALE;
  const int wm = (wave & 1) * 64;
  const int wn = (wave >> 1) * 64;

  f4 acc[4][4];
#pragma unroll
  for (int i = 0; i < 4; ++i)
#pragma unroll
    for (int j = 0; j < 4; ++j) acc[i][j] = (f4){0.f, 0.f, 0.f, 0.f};

  const short* ag = X + (size_t)(m0 + (t >> 2)) * 1024 + (t & 3) * 8;
  const short* bg = W + (size_t)(n0l + (t >> 2)) * 1024 + (t & 3) * 8;
  short* al = As + wave * 512;
  short* bl = Bs + wave * 512;

  for (int kt = 0; kt < 1024; kt += 32) {
    __syncthreads();
    GLDS16(ag + kt, al);
    GLDS16(ag + 65536 + kt, al + 2048);
    GLDS16(bg + kt, bl);
    GLDS16(bg + 65536 + kt, bl + 2048);
    __syncthreads();
    sh8 af[4], bf[4];
#pragma unroll
    for (int i = 0; i < 4; ++i) {
      af[i] = *(const sh8*)(As + (wm + i * 16 + l15) * 32 + quad * 8);
      bf[i] = *(const sh8*)(Bs + (wn + i * 16 + l15) * 32 + quad * 8);
    }
#pragma unroll
    for (int i = 0; i < 4; ++i)
#pragma unroll
      for (int j = 0; j < 4; ++j)
        acc[i][j] =
            __builtin_amdgcn_mfma_f32_16x16x32_bf16(af[i], bf[j], acc[i][j], 0, 0, 0);
  }

#pragma unroll
  for (int j = 0; j < 4; ++j) {
    const int ngl = n0l + wn + j * 16 + l15;
    const float bias = Bias[ngl];
    const int hl = ngl >> 6;
    const int d = ngl & 63;
#pragma unroll
    for (int i = 0; i < 4; ++i) {
#pragma unroll
      for (int r = 0; r < 4; ++r) {
        const int m = m0 + wm + i * 16 + quad * 4 + r;
        const int slot = (m >> 11) * 16 + hl;
        const int mm = m & 2047;
        const short o = f2bf((acc[i][j][r] + bias) * qkscl);
        if (which == 0)
          Qp[((size_t)slot * 2048 + mm) * 64 + d] = o;
        else if (which == 1)
          Kp[((size_t)slot * 2048 + mm) * 64 + d] = o;
        else
          Vtp[((size_t)slot * 64 + d) * 2048 + mm] = o;
      }
    }
  }
}

// ---------------------------------------------------------------------------
// Sums of squares of bf16-rounded (scaled) Q and K rows. R rows per tensor.
// ---------------------------------------------------------------------------
__global__ __launch_bounds__(256) void sumsq(const short* __restrict__ Qp,
                                             const short* __restrict__ Kp,
                                             float* __restrict__ q2a,
                                             float* __restrict__ k2a, int R) {
  const int tid = blockIdx.x * 256 + threadIdx.x;
  const bool isQ = tid < R;
  const int r = isQ ? tid : tid - R;
  const short* p = (isQ ? Qp : Kp) + (size_t)r * 64;
  float s = 0.f;
#pragma unroll
  for (int i = 0; i < 8; ++i) {
    sh8 v = *(const sh8*)(p + i * 8);
#pragma unroll
    for (int j = 0; j < 8; ++j) {
      float f = bf2f(v[j]);
      s = fmaf(f, f, s);
    }
  }
  (isQ ? q2a : k2a)[r] = s;
}

// ---------------------------------------------------------------------------
// attn5: LDS-staged flash attention, fixed max=0, 32 queries per wave,
// 4-wave blocks (128 q). Flat 512-block grid with XCD-aware decode:
//   xcd = id&7 (HW round-robin), each XCD owns 4 head-slots entirely
//   (16 qt blocks each) -> K+V working set 2MB fits the XCD's 4MB L2.
//   qt = (id>>3)&15, slot hb = (id&7)*4 + (id>>7), bz = hb>>4, hy = hb&15.
// K/V tiles of 128 keys staged to XOR-swizzled LDS:
//   Ks[128 rows][64 shorts]  (row = key, 8 chunks of 16B, chunk ^= row&7)
//   Vs[64 rows][128 shorts]  (row = vdim, 16 chunks of 16B, chunk ^= row&7)
// S^T = MFMA(A=Kfrag, B=Qfrag): C row=key(quad*4+r), col=query(l15) ==
// A-layout of P for 16x16x16 PV. O C-layout: row=query, col=vdim chunk.
// Inputs pre-scaled by log2(e): p = exp2(-sqrt(|d2'|)).
// ---------------------------------------------------------------------------
__global__ __launch_bounds__(256, 2) void attn5(
    const short* __restrict__ Qp, const short* __restrict__ Kp,
    const short* __restrict__ Vtp, const float* __restrict__ q2a,
    const float* __restrict__ k2a, short* __restrict__ attH) {
  __shared__ short Ks[128 * 64];   // 16 KB
  __shared__ short Vs[64 * 128];   // 16 KB
  const int t = threadIdx.x;
  const int wave = t >> 6;
  const int lane = t & 63;
  const int l15 = lane & 15;
  const int quad = lane >> 4;
  const int id = blockIdx.x;             // [0,512)
  const int qt = (id >> 3) & 15;         // query tile
  const int hb_ = (id & 7) * 4 + (id >> 7);  // slot [0,32): xcd owns 4 slots
  const int hy = hb_ & 15;
  const int bz = hb_ >> 4;
  const size_t hb = (size_t)hb_;
  const size_t base = hb * 2048;
  const int qrowA = qt * 128 + wave * 32 + l15;
  const int qrowB = qrowA + 16;

  const short* qpA = Qp + (base + qrowA) * 64 + quad * 8;
  const sh8 qA0 = *(const sh8*)qpA;
  const sh8 qA1 = *(const sh8*)(qpA + 32);
  const short* qpB = Qp + (base + qrowB) * 64 + quad * 8;
  const sh8 qB0 = *(const sh8*)qpB;
  const sh8 qB1 = *(const sh8*)(qpB + 32);
  const float q2A = q2a[base + qrowA];
  const float q2B = q2a[base + qrowB];

  float lA = 0.f, lB = 0.f;
  f4 oA0 = (f4){0.f, 0.f, 0.f, 0.f}, oA1 = oA0, oA2 = oA0, oA3 = oA0;
  f4 oB0 = oA0, oB1 = oA0, oB2 = oA0, oB3 = oA0;

  const float* k2p = k2a + base + quad * 4;

  // staging geometry (256 threads): K rows t>>3 (+32,+64,+96) chunk t&7;
  // V rows t>>4 (+16,+32,+48) chunk t&15. Swizzled LDS indices precomputed.
  const int kr = t >> 3, kc = t & 7;
  const int vr = t >> 4, vc = t & 15;
  const short* kg0 = Kp + (base + kr) * 64 + kc * 8;
  const short* vg0 = Vtp + (hb * 64 + vr) * 2048 + vc * 8;
  const int kidx = kr * 64 + ((kc ^ (kr & 7)) * 8);   // (kr+32i)&7 == kr&7
  const int vidx = vr * 128 + ((vc ^ (vr & 7)) * 8);  // (vr+16i)&7 == vr&7

  // prefetch tile 0 into registers
  sh8 kp0 = *(const sh8*)kg0;
  sh8 kp1 = *(const sh8*)(kg0 + 32 * 64);
  sh8 kp2 = *(const sh8*)(kg0 + 64 * 64);
  sh8 kp3 = *(const sh8*)(kg0 + 96 * 64);
  sh8 vp0 = *(const sh8*)vg0;
  sh8 vp1 = *(const sh8*)(vg0 + 16 * 2048);
  sh8 vp2 = *(const sh8*)(vg0 + 32 * 2048);
  sh8 vp3 = *(const sh8*)(vg0 + 48 * 2048);

  for (int k0 = 0; k0 < 2048; k0 += 128) {
    __syncthreads();
    *(sh8*)(Ks + kidx) = kp0;
    *(sh8*)(Ks + 32 * 64 + kidx) = kp1;
    *(sh8*)(Ks + 64 * 64 + kidx) = kp2;
    *(sh8*)(Ks + 96 * 64 + kidx) = kp3;
    *(sh8*)(Vs + vidx) = vp0;
    *(sh8*)(Vs + 16 * 128 + vidx) = vp1;
    *(sh8*)(Vs + 32 * 128 + vidx) = vp2;
    *(sh8*)(Vs + 48 * 128 + vidx) = vp3;
    __syncthreads();
    if (k0 + 128 < 2048) {   // issue next tile's loads; land during compute
      const short* kg = kg0 + (size_t)(k0 + 128) * 64;
      kp0 = *(const sh8*)kg;
      kp1 = *(const sh8*)(kg + 32 * 64);
      kp2 = *(const sh8*)(kg + 64 * 64);
      kp3 = *(const sh8*)(kg + 96 * 64);
      const short* vg = vg0 + k0 + 128;
      vp0 = *(const sh8*)vg;
      vp1 = *(const sh8*)(vg + 16 * 2048);
      vp2 = *(const sh8*)(vg + 32 * 2048);
      vp3 = *(const sh8*)(vg + 48 * 2048);
    }

#pragma unroll
    for (int sub = 0; sub < 8; ++sub) {
      const int j = sub * 16;
      const int krow = j + l15;
      const int kcs = (quad ^ (krow & 7)) * 8;
      const sh8 kf0 = *(const sh8*)(Ks + krow * 64 + kcs);
      const sh8 kf1 = *(const sh8*)(Ks + krow * 64 + (kcs ^ 32));
      f4 stA = (f4){0.f, 0.f, 0.f, 0.f};
      f4 stB = (f4){0.f, 0.f, 0.f, 0.f};
      stA = __builtin_amdgcn_mfma_f32_16x16x32_bf16(kf0, qA0, stA, 0, 0, 0);
      stA = __builtin_amdgcn_mfma_f32_16x16x32_bf16(kf1, qA1, stA, 0, 0, 0);
      stB = __builtin_amdgcn_mfma_f32_16x16x32_bf16(kf0, qB0, stB, 0, 0, 0);
      stB = __builtin_amdgcn_mfma_f32_16x16x32_bf16(kf1, qB1, stB, 0, 0, 0);
      const f4 k2v = *(const f4*)(k2p + k0 + j);
      float pA[4], pB[4];
#pragma unroll
      for (int r = 0; r < 4; ++r) {
        const float dA = fmaf(-2.f, stA[r], q2A + k2v[r]);
        pA[r] = exp2neg(__builtin_amdgcn_sqrtf(fabsf(dA)));
        const float dB = fmaf(-2.f, stB[r], q2B + k2v[r]);
        pB[r] = exp2neg(__builtin_amdgcn_sqrtf(fabsf(dB)));
      }
      lA += (pA[0] + pA[1]) + (pA[2] + pA[3]);
      lB += (pB[0] + pB[1]) + (pB[2] + pB[3]);
      sh4 pfA, pfB;
#pragma unroll
      for (int r = 0; r < 4; ++r) {
        pfA[r] = f2bf(pA[r]);
        pfB[r] = f2bf(pB[r]);
      }
      // V reads: logical row=l15+16c, cols j+quad*4 (8B within 16B chunk
      // sub*2 + (quad>>1)); swizzle chunk with row&7 == l15&7.
      const int vcol = ((sub * 2 + (quad >> 1)) ^ (l15 & 7)) * 8 + (quad & 1) * 4;
      const sh4 vf0 = *(const sh4*)(Vs + l15 * 128 + vcol);
      const sh4 vf1 = *(const sh4*)(Vs + (l15 + 16) * 128 + vcol);
      const sh4 vf2 = *(const sh4*)(Vs + (l15 + 32) * 128 + vcol);
      const sh4 vf3 = *(const sh4*)(Vs + (l15 + 48) * 128 + vcol);
      oA0 = __builtin_amdgcn_mfma_f32_16x16x16bf16_1k(pfA, vf0, oA0, 0, 0, 0);
      oA1 = __builtin_amdgcn_mfma_f32_16x16x16bf16_1k(pfA, vf1, oA1, 0, 0, 0);
      oA2 = __builtin_amdgcn_mfma_f32_16x16x16bf16_1k(pfA, vf2, oA2, 0, 0, 0);
      oA3 = __builtin_amdgcn_mfma_f32_16x16x16bf16_1k(pfA, vf3, oA3, 0, 0, 0);
      oB0 = __builtin_amdgcn_mfma_f32_16x16x16bf16_1k(pfB, vf0, oB0, 0, 0, 0);
      oB1 = __builtin_amdgcn_mfma_f32_16x16x16bf16_1k(pfB, vf1, oB1, 0, 0, 0);
      oB2 = __builtin_amdgcn_mfma_f32_16x16x16bf16_1k(pfB, vf2, oB2, 0, 0, 0);
      oB3 = __builtin_amdgcn_mfma_f32_16x16x16bf16_1k(pfB, vf3, oB3, 0, 0, 0);
    }
  }

  lA += __shfl_xor(lA, 16);
  lA += __shfl_xor(lA, 32);
  lB += __shfl_xor(lB, 16);
  lB += __shfl_xor(lB, 32);
  float ilA[4], ilB[4];
#pragma unroll
  for (int r = 0; r < 4; ++r) {
    ilA[r] = 1.f / __shfl(lA, quad * 4 + r);
    ilB[r] = 1.f / __shfl(lB, quad * 4 + r);
  }

  const int rbA = qt * 128 + wave * 32 + quad * 4;
  const size_t offA = ((size_t)bz * 2048 + rbA) * 1024 + hy * 64 + l15;
  const size_t offB = offA + (size_t)16 * 1024;
  const f4* ocA[4] = {&oA0, &oA1, &oA2, &oA3};
  const f4* ocB[4] = {&oB0, &oB1, &oB2, &oB3};
#pragma unroll
  for (int c = 0; c < 4; ++c)
#pragma unroll
    for (int r = 0; r < 4; ++r) {
      attH[offA + (size_t)r * 1024 + c * 16] = f2bf((*ocA[c])[r] * ilA[r]);
      attH[offB + (size_t)r * 1024 + c * 16] = f2bf((*ocB[c])[r] * ilB[r]);
    }
}

// ---------------------------------------------------------------------------
// attn (global-load variant) for Tier C only: fp32 att into d_out slice.
// Inputs pre-scaled by log2(e): exp2 path.
// ---------------------------------------------------------------------------
__global__ __launch_bounds__(256) void attn_c(
    const short* __restrict__ Qp, const short* __restrict__ Kp,
    const short* __restrict__ Vtp, const float* __restrict__ q2a,
    const float* __restrict__ k2a, float* __restrict__ attF, int col0) {
  const int t = threadIdx.x;
  const int wave = t >> 6;
  const int lane = t & 63;
  const int l15 = lane & 15;
  const int quad = lane >> 4;
  const int hy = blockIdx.y;
  const int qt = blockIdx.x;
  const size_t base = (size_t)hy * 2048;
  const int qrow = qt * 64 + wave * 16 + l15;

  const short* qp = Qp + (base + qrow) * 64 + quad * 8;
  const sh8 qf0 = *(const sh8*)qp;
  const sh8 qf1 = *(const sh8*)(qp + 32);
  const float q2 = q2a[base + qrow];

  float l_run = 0.f;
  f4 o0 = (f4){0.f, 0.f, 0.f, 0.f}, o1 = o0, o2 = o0, o3 = o0;

  const short* kbase = Kp + (base + l15) * 64 + quad * 8;
  const float* k2p = k2a + base + quad * 4;
  const short* vbase = Vtp + ((size_t)hy * 64 + l15) * 2048 + quad * 4;

  for (int j = 0; j < 2048; j += 16) {
    const sh8 kf0 = *(const sh8*)(kbase + (size_t)j * 64);
    const sh8 kf1 = *(const sh8*)(kbase + (size_t)j * 64 + 32);
    f4 st = (f4){0.f, 0.f, 0.f, 0.f};
    st = __builtin_amdgcn_mfma_f32_16x16x32_bf16(kf0, qf0, st, 0, 0, 0);
    st = __builtin_amdgcn_mfma_f32_16x16x32_bf16(kf1, qf1, st, 0, 0, 0);
    const f4 k2v = *(const f4*)(k2p + j);
    float p[4];
#pragma unroll
    for (int r = 0; r < 4; ++r) {
      const float d2 = fmaxf(fmaf(-2.f, st[r], q2 + k2v[r]), D2_CLAMP);
      p[r] = exp2neg(__builtin_amdgcn_sqrtf(d2));
    }
    l_run += (p[0] + p[1]) + (p[2] + p[3]);
    sh4 pf;
#pragma unroll
    for (int r = 0; r < 4; ++r) pf[r] = f2bf(p[r]);
    const sh4 vf0 = *(const sh4*)(vbase + j);
    const sh4 vf1 = *(const sh4*)(vbase + 16 * 2048 + j);
    const sh4 vf2 = *(const sh4*)(vbase + 32 * 2048 + j);
    const sh4 vf3 = *(const sh4*)(vbase + 48 * 2048 + j);
    o0 = __builtin_amdgcn_mfma_f32_16x16x16bf16_1k(pf, vf0, o0, 0, 0, 0);
    o1 = __builtin_amdgcn_mfma_f32_16x16x16bf16_1k(pf, vf1, o1, 0, 0, 0);
    o2 = __builtin_amdgcn_mfma_f32_16x16x16bf16_1k(pf, vf2, o2, 0, 0, 0);
    o3 = __builtin_amdgcn_mfma_f32_16x16x16bf16_1k(pf, vf3, o3, 0, 0, 0);
  }

  l_run += __shfl_xor(l_run, 16);
  l_run += __shfl_xor(l_run, 32);
  const float il0 = 1.f / __shfl(l_run, quad * 4 + 0);
  const float il1 = 1.f / __shfl(l_run, quad * 4 + 1);
  const float il2 = 1.f / __shfl(l_run, quad * 4 + 2);
  const float il3 = 1.f / __shfl(l_run, quad * 4 + 3);

  const int rowbase = qt * 64 + wave * 16 + quad * 4;
  const f4* oc[4] = {&o0, &o1, &o2, &o3};
  const float il[4] = {il0, il1, il2, il3};
  const size_t off0 = (size_t)rowbase * 1024 + col0 + hy * 64 + l15;
#pragma unroll
  for (int c = 0; c < 4; ++c)
#pragma unroll
    for (int r = 0; r < 4; ++r)
      attF[off0 + (size_t)r * 1024 + c * 16] = (*oc[c])[r] * il[r];
}

// ---------------------------------------------------------------------------
// Output projection, 64x128 tile (512 blocks = 2/CU). Tier A2: bf16 Wo.
// Wave tile 32x64: acc[2][4].
// ---------------------------------------------------------------------------
__global__ __launch_bounds__(256) void gemm_out_bf64(
    const short* __restrict__ A, const short* __restrict__ W,
    const float* __restrict__ Bias, float* __restrict__ Out) {
  __shared__ short As[64 * 32];
  __shared__ short Bs[128 * 32];
  const int t = threadIdx.x;
  const int wave = t >> 6;
  const int lane = t & 63;
  const int l15 = lane & 15;
  const int quad = lane >> 4;
  const int m0 = blockIdx.y * 64;
  const int n0 = blockIdx.x * 128;
  const int wm = (wave & 1) * 32;
  const int wn = (wave >> 1) * 64;

  f4 acc[2][4];
#pragma unroll
  for (int i = 0; i < 2; ++i)
#pragma unroll
    for (int j = 0; j < 4; ++j) acc[i][j] = (f4){0.f, 0.f, 0.f, 0.f};

  const short* ag = A + (size_t)(m0 + (t >> 2)) * 1024 + (t & 3) * 8;
  const short* bg = W + (size_t)(n0 + (t >> 2)) * 1024 + (t & 3) * 8;
  short* al = As + wave * 512;
  short* bl = Bs + wave * 512;

  for (int kt = 0; kt < 1024; kt += 32) {
    __syncthreads();
    GLDS16(ag + kt, al);          // A: 64x32 = one issue
    GLDS16(bg + kt, bl);          // B: 128x32 = two issues
    GLDS16(bg + 65536 + kt, bl + 2048);
    __syncthreads();
    sh8 af[2], bf[4];
#pragma unroll
    for (int i = 0; i < 2; ++i)
      af[i] = *(const sh8*)(As + (wm + i * 16 + l15) * 32 + quad * 8);
#pragma unroll
    for (int j = 0; j < 4; ++j)
      bf[j] = *(const sh8*)(Bs + (wn + j * 16 + l15) * 32 + quad * 8);
#pragma unroll
    for (int i = 0; i < 2; ++i)
#pragma unroll
      for (int j = 0; j < 4; ++j)
        acc[i][j] =
            __builtin_amdgcn_mfma_f32_16x16x32_bf16(af[i], bf[j], acc[i][j], 0, 0, 0);
  }

#pragma unroll
  for (int j = 0; j < 4; ++j) {
    const int n = n0 + wn + j * 16 + l15;
    const float bias = Bias[n];
#pragma unroll
    for (int i = 0; i < 2; ++i) {
#pragma unroll
      for (int r = 0; r < 4; ++r) {
        const int m = m0 + wm + i * 16 + quad * 4 + r;
        Out[(size_t)m * 1024 + n] = acc[i][j][r] + bias;
      }
    }
  }
}

// Tier A variant: fp32 Wo with pack8 staging, same 64x128 tile.
__global__ __launch_bounds__(256) void gemm_out_ws64(
    const short* __restrict__ A, const float* __restrict__ W,
    const float* __restrict__ Bias, float* __restrict__ Out) {
  __shared__ short As[64 * 32];
  __shared__ short Bs[128 * 32];
  const int t = threadIdx.x;
  const int wave = t >> 6;
  const int lane = t & 63;
  const int l15 = lane & 15;
  const int quad = lane >> 4;
  const int m0 = blockIdx.y * 64;
  const int n0 = blockIdx.x * 128;
  const int wm = (wave & 1) * 32;
  const int wn = (wave >> 1) * 64;

  f4 acc[2][4];
#pragma unroll
  for (int i = 0; i < 2; ++i)
#pragma unroll
    for (int j = 0; j < 4; ++j) acc[i][j] = (f4){0.f, 0.f, 0.f, 0.f};

  const short* ag = A + (size_t)(m0 + (t >> 2)) * 1024 + (t & 3) * 8;
  const float* bg = W + (size_t)(n0 + (t >> 2)) * 1024 + (t & 3) * 8;
  short* al = As + wave * 512;

  for (int kt = 0; kt < 1024; kt += 32) {
    const sh8 b0 = pack8(*(const f4*)(bg + kt), *(const f4*)(bg + kt + 4));
    const sh8 b1 =
        pack8(*(const f4*)(bg + 65536 + kt), *(const f4*)(bg + 65536 + kt + 4));
    __syncthreads();
    GLDS16(ag + kt, al);
    *(sh8*)(Bs + t * 8) = b0;
    *(sh8*)(Bs + 2048 + t * 8) = b1;
    __syncthreads();
    sh8 af[2], bf[4];
#pragma unroll
    for (int i = 0; i < 2; ++i)
      af[i] = *(const sh8*)(As + (wm + i * 16 + l15) * 32 + quad * 8);
#pragma unroll
    for (int j = 0; j < 4; ++j)
      bf[j] = *(const sh8*)(Bs + (wn + j * 16 + l15) * 32 + quad * 8);
#pragma unroll
    for (int i = 0; i < 2; ++i)
#pragma unroll
      for (int j = 0; j < 4; ++j)
        acc[i][j] =
            __builtin_amdgcn_mfma_f32_16x16x32_bf16(af[i], bf[j], acc[i][j], 0, 0, 0);
  }

#pragma unroll
  for (int j = 0; j < 4; ++j) {
    const int n = n0 + wn + j * 16 + l15;
    const float bias = Bias[n];
#pragma unroll
    for (int i = 0; i < 2; ++i) {
#pragma unroll
      for (int r = 0; r < 4; ++r) {
        const int m = m0 + wm + i * 16 + quad * 4 + r;
        Out[(size_t)m * 1024 + n] = acc[i][j][r] + bias;
      }
    }
  }
}

// ---------------------------------------------------------------------------
// Fallback in-place output projection (Tier C).
// ---------------------------------------------------------------------------
__global__ __launch_bounds__(256) void outproj_inplace(
    float* __restrict__ AO, const float* __restrict__ W,
    const float* __restrict__ Bias) {
  __shared__ short attS[16 * 264];
  const int t = threadIdx.x;
  const int wave = t >> 6;
  const int lane = t & 63;
  const int l15 = lane & 15;
  const int quad = lane >> 4;
  const int m0 = blockIdx.x * 16;
  const int n0w = wave * 256;

  f4 acc[16];
#pragma unroll
  for (int i = 0; i < 16; ++i) acc[i] = (f4){0.f, 0.f, 0.f, 0.f};

  for (int kc = 0; kc < 4; ++kc) {
    __syncthreads();
#pragma unroll
    for (int i = 0; i < 2; ++i) {
      const int e = i * 2048 + t * 8;
      const int row = e >> 8;
      const int col = e & 255;
      const float* src = AO + (size_t)(m0 + row) * 1024 + kc * 256 + col;
      *(sh8*)(attS + row * 264 + col) =
          pack8(*(const f4*)src, *(const f4*)(src + 4));
    }
    __syncthreads();
    for (int ktl = 0; ktl < 256; ktl += 32) {
      const sh8 af = *(const sh8*)(attS + l15 * 264 + ktl + quad * 8);
      const int kt = kc * 256 + ktl;
#pragma unroll
      for (int nf = 0; nf < 16; ++nf) {
        const float* wp = W + (size_t)(n0w + nf * 16 + l15) * 1024 + kt + quad * 8;
        const sh8 bf = pack8(*(const f4*)wp, *(const f4*)(wp + 4));
        acc[nf] = __builtin_amdgcn_mfma_f32_16x16x32_bf16(af, bf, acc[nf], 0, 0, 0);
      }
    }
  }
  __syncthreads();

#pragma unroll
  for (int nf = 0; nf < 16; ++nf) {
    const int n = n0w + nf * 16 + l15;
    const float bias = Bias[n];
#pragma unroll
    for (int r = 0; r < 4; ++r) {
      const int m = m0 + quad * 4 + r;
      AO[(size_t)m * 1024 + n] = acc[nf][r] + bias;
    }
  }
}

// ---------------------------------------------------------------------------
extern "C" void kernel_launch(void* const* d_in, const int* in_sizes, int n_in,
                              void* d_out, int out_size, void* d_ws,
                              size_t ws_size, hipStream_t stream) {
  const float* x = (const float*)d_in[0];
  const float* wq = (const float*)d_in[1];
  const float* bq = (const float*)d_in[2];
  const float* wk = (const float*)d_in[3];
  const float* bk = (const float*)d_in[4];
  const float* wv = (const float*)d_in[5];
  const float* bv = (const float*)d_in[6];
  const float* wo = (const float*)d_in[7];
  const float* bo = (const float*)d_in[8];
  float* out = (float*)d_out;

  const size_t NEED_A2 = 50855936ULL;  // A + Xbf 8MB + Wbf 8MB
  const size_t NEED_A = 34078720ULL;   // 24MB QKV(2b) + 8MB att + 512KB q2k2

  if (ws_size >= NEED_A) {
    short* Qp = (short*)d_ws;                 // [b*16+h][2048][64] bf16, 8MB
    short* Kp = Qp + 4194304;                 // 8MB
    short* Vtp = Kp + 4194304;                // [b*16+h][64][2048] bf16, 8MB
    short* attAll = Vtp + 4194304;            // [4096][1024] bf16, 8MB
    float* q2 = (float*)(attAll + 4194304);   // 256KB
    float* k2 = q2 + 65536;                   // 256KB

    if (ws_size >= NEED_A2) {
      short* Xb = (short*)(k2 + 65536);       // 4M bf16 = 8MB
      short* Wqb = Xb + 4194304;              // 4x 1M bf16, contiguous
      cvt_bf16<<<2048, 256, 0, stream>>>(x, Xb, 4194304);
      cvt_w4<<<dim3(512, 4), 256, 0, stream>>>(wq, wk, wv, wo, Wqb);
      gemm_qkv_bf<<<dim3(24, 32), 256, 0, stream>>>(
          Xb, Wqb, bq, Wqb + 1048576, bk, Wqb + 2097152, bv, Qp, Kp, Vtp);
      sumsq<<<512, 256, 0, stream>>>(Qp, Kp, q2, k2, 65536);
      attn5<<<512, 256, 0, stream>>>(Qp, Kp, Vtp, q2, k2, attAll);
      gemm_out_bf64<<<dim3(8, 64), 256, 0, stream>>>(attAll, Wqb + 3145728,
                                                     bo, out);
    } else {
      gemm_qkvp<<<dim3(24, 32), 256, 0, stream>>>(x, wq, bq, wk, bk, wv, bv,
                                                  Qp, Kp, Vtp, 0, 8);
      sumsq<<<512, 256, 0, stream>>>(Qp, Kp, q2, k2, 65536);
      attn5<<<512, 256, 0, stream>>>(Qp, Kp, Vtp, q2, k2, attAll);
      gemm_out_ws64<<<dim3(8, 64), 256, 0, stream>>>(attAll, wo, bo, out);
    }
  } else {
    // Tier C: small-ws fallback (att fp32 in d_out, in-place outproj).
    int G = 16;
    while (G > 2 && (size_t)G * 802816ULL > ws_size) G >>= 1;
    short* Qp = (short*)d_ws;
    short* Kp = Qp + (size_t)G * 131072;
    short* Vtp = Kp + (size_t)G * 131072;
    float* q2 = (float*)(Vtp + (size_t)G * 131072);
    float* k2 = q2 + (size_t)G * 2048;

    const int groups = 16 / G;
    for (int b = 0; b < 2; ++b) {
      const float* xb = x + (size_t)b * 2097152;
      float* attB = out + (size_t)b * 2097152;
      for (int g = 0; g < groups; ++g) {
        gemm_qkvp<<<dim3(3 * (G / 2), 16), 256, 0, stream>>>(
            xb, wq, bq, wk, bk, wv, bv, Qp, Kp, Vtp, g * G * 64, G / 2);
        sumsq<<<16 * G, 256, 0, stream>>>(Qp, Kp, q2, k2, G * 2048);
        attn_c<<<dim3(32, G), 256, 0, stream>>>(Qp, Kp, Vtp, q2, k2, attB,
                                                g * G * 64);
      }
    }
    outproj_inplace<<<256, 256, 0, stream>>>(out, wo, bo);
  }
}